// Round 3
// baseline (287.424 us; speedup 1.0000x reference)
//
#include <hip/hip_runtime.h>

typedef __bf16 bf16x8 __attribute__((ext_vector_type(8)));
typedef float f32x4 __attribute__((ext_vector_type(4)));
typedef float f32x2 __attribute__((ext_vector_type(2)));
typedef unsigned int u32x4 __attribute__((ext_vector_type(4)));
typedef unsigned int u32x2 __attribute__((ext_vector_type(2)));

#define HW 14400
#define CIN 192

__device__ __forceinline__ unsigned short f2bf(float f) {
  unsigned int u = __builtin_bit_cast(unsigned int, f);
  u = (u + 0x7FFFu + ((u >> 16) & 1u)) >> 16;
  return (unsigned short)u;
}
__device__ __forceinline__ float bf2f(unsigned short h) {
  unsigned int u = ((unsigned int)h) << 16;
  return __builtin_bit_cast(float, u);
}

// ---------------- prep: fold BN into conv weights, convert to bf16 ----------
// wo gets k-permuted to match the s-space layout of z: within each 64-block,
// stored index s holds true channel (s&3)*16 + (s>>2).
__global__ void prep_kernel(const float* __restrict__ w_in, const float* __restrict__ b_in,
                            const float* __restrict__ g, const float* __restrict__ be,
                            const float* __restrict__ mu, const float* __restrict__ va,
                            const float* __restrict__ w_out,
                            unsigned short* __restrict__ wx, unsigned short* __restrict__ wy,
                            unsigned short* __restrict__ wo,
                            float* __restrict__ bx, float* __restrict__ by) {
  int idx = blockIdx.x * 256 + threadIdx.x;
  if (idx < 384 * 192) {
    int o = idx / 192;
    float s = g[o] * rsqrtf(va[o] + 1e-5f);
    wx[idx] = f2bf(w_in[idx] * s);
  } else if (idx < 384 * 192 + 192 * 192) {
    int j = idx - 384 * 192;
    int jo = j / 192, c = j % 192;
    int o = (jo >> 6) * 128 + (jo & 63);   // q-channel rows only
    float s = g[o] * rsqrtf(va[o] + 1e-5f);
    wy[j] = f2bf(w_in[o * 192 + c] * s);
  } else if (idx < 384 * 192 + 2 * 192 * 192) {
    int j = idx - (384 * 192 + 192 * 192);
    int o = j / 192, cs = j % 192;
    int s = cs & 63;
    int src = (cs & ~63) | ((s & 3) * 16 + (s >> 2));
    wo[j] = f2bf(w_out[o * 192 + src]);
  }
  if (idx < 384) {
    float s = g[idx] * rsqrtf(va[idx] + 1e-5f);
    bx[idx] = (b_in[idx] - mu[idx]) * s + be[idx];
  } else if (idx < 384 + 192) {
    int jo = idx - 384;
    int o = (jo >> 6) * 128 + (jo & 63);
    float s = g[o] * rsqrtf(va[o] + 1e-5f);
    by[jo] = (b_in[o] - mu[o]) * s + be[o];
  }
}

// ---------------- conv_in: [b,c,h,w] fp32 -> [px][NOUT] bf16 (s-permuted) ---
// 6 waves; each wave owns a 64-out chunk (NOUT=384: 1 px-span of 64; NOUT=192:
// 3 chunks x 2 px-halves). A staged via dbuf LDS transpose (b64 writes),
// weights direct-from-global fragments, packed b64 output stores.
template <int NOUT>
__launch_bounds__(384, 2)
__global__ void conv_in_kernel(const float* __restrict__ X,
                               const unsigned short* __restrict__ Wb,
                               const float* __restrict__ bias,
                               unsigned short* __restrict__ Out) {
  constexpr int M = (NOUT == 384) ? 4 : 2;
  __shared__ unsigned short a_lds[2][64 * 40];
  const int t = threadIdx.x;
  const int wave = t >> 6, lane = t & 63, l15 = lane & 15, l4 = lane >> 4;
  const int wchunk = (NOUT == 384) ? wave : (wave >> 1);
  const int px_base = (NOUT == 384) ? 0 : ((wave & 1) * 32);
  const int wo0 = wchunk * 64;
  const int b = blockIdx.x / 225;
  const int px0 = (blockIdx.x % 225) * 64;
  const float* Xb = X + (size_t)b * CIN * HW + px0;

  f32x4 acc[M][4];
#pragma unroll
  for (int n = 0; n < 4; ++n) {
    float bv = bias[wo0 + n * 16 + l15];
#pragma unroll
    for (int m = 0; m < M; ++m) acc[m][n] = f32x4{bv, bv, bv, bv};
  }

  const int c_off = (t & 7) * 4, px2 = ((t >> 3) & 31) * 2;
  auto stage = [&](int kc, int buf) {
    if (t < 256) {
      const float* src = Xb + (size_t)(kc * 32 + c_off) * HW + px2;
      f32x2 v0 = *reinterpret_cast<const f32x2*>(src);
      f32x2 v1 = *reinterpret_cast<const f32x2*>(src + HW);
      f32x2 v2 = *reinterpret_cast<const f32x2*>(src + 2 * HW);
      f32x2 v3 = *reinterpret_cast<const f32x2*>(src + 3 * HW);
      u32x2 r0 = {(unsigned)f2bf(v0[0]) | ((unsigned)f2bf(v1[0]) << 16),
                  (unsigned)f2bf(v2[0]) | ((unsigned)f2bf(v3[0]) << 16)};
      u32x2 r1 = {(unsigned)f2bf(v0[1]) | ((unsigned)f2bf(v1[1]) << 16),
                  (unsigned)f2bf(v2[1]) | ((unsigned)f2bf(v3[1]) << 16)};
      *reinterpret_cast<u32x2*>(&a_lds[buf][px2 * 40 + c_off]) = r0;
      *reinterpret_cast<u32x2*>(&a_lds[buf][(px2 + 1) * 40 + c_off]) = r1;
    }
  };
  auto loadW = [&](int kc, int n) {
    return *reinterpret_cast<const bf16x8*>(
        Wb + (size_t)(wo0 + n * 16 + l15) * CIN + kc * 32 + l4 * 8);
  };

  stage(0, 0);
  bf16x8 bw[4], bwn[4];
#pragma unroll
  for (int n = 0; n < 4; ++n) bw[n] = loadW(0, n);

  for (int kc = 0; kc < 6; ++kc) {
    __syncthreads();
    if (kc < 5) {
      stage(kc + 1, (kc + 1) & 1);
#pragma unroll
      for (int n = 0; n < 4; ++n) bwn[n] = loadW(kc + 1, n);
    }
    bf16x8 af[M];
#pragma unroll
    for (int m = 0; m < M; ++m)
      af[m] = *reinterpret_cast<const bf16x8*>(
          &a_lds[kc & 1][(px_base + m * 16 + l15) * 40 + l4 * 8]);
#pragma unroll
    for (int n = 0; n < 4; ++n)
#pragma unroll
      for (int m = 0; m < M; ++m)
        acc[m][n] = __builtin_amdgcn_mfma_f32_16x16x32_bf16(af[m], bw[n], acc[m][n], 0, 0, 0);
#pragma unroll
    for (int n = 0; n < 4; ++n) bw[n] = bwn[n];
  }

  // packed store: s = l15*4 + n (o = (s&3)*16 + s>>2 within the 64-chunk)
#pragma unroll
  for (int m = 0; m < M; ++m) {
#pragma unroll
    for (int r = 0; r < 4; ++r) {
      int px = px_base + m * 16 + l4 * 4 + r;
      u32x2 pk = {(unsigned)f2bf(acc[m][0][r]) | ((unsigned)f2bf(acc[m][1][r]) << 16),
                  (unsigned)f2bf(acc[m][2][r]) | ((unsigned)f2bf(acc[m][3][r]) << 16)};
      *reinterpret_cast<u32x2*>(Out + ((size_t)b * HW + px0 + px) * NOUT + wo0 + l15 * 4) = pk;
    }
  }
}

// ---------------- attention generic (ws 8/12): reg S, shfl softmax, MFMA PV -
template <int WS, int SI, int NTHR>
__launch_bounds__(NTHR, 2)
__global__ void attn_kernel(const unsigned short* __restrict__ XP,
                            const unsigned short* __restrict__ YQ,
                            unsigned short* __restrict__ Z,
                            float* __restrict__ ATN) {
  constexpr int S = WS / 2, L = WS * WS, NH = 120 / WS, TT = L / 16;
  constexpr int NWAVE = NTHR / 64;
  constexpr int SMAX = (TT + NWAVE - 1) / NWAVE;
  constexpr int KP = ((L + 31) / 32) * 32;
  constexpr int PL = KP + 8;
  constexpr int KSTEPS = KP / 32;
  constexpr int POOLE = (L * 72 > L * PL) ? L * 72 : L * PL;
  __shared__ unsigned short pool[POOLE];
  __shared__ unsigned short vt_lds[64 * PL];
  unsigned short* k_lds = pool;
  unsigned short* p_lds = pool;

  const int t = threadIdx.x;
  const int win = blockIdx.x;
  const int b = win / (NH * NH);
  const int r_ = win % (NH * NH);
  const int ih = r_ / NH, iw = r_ % NH;
  const int wave = t >> 6, lane = t & 63, l15 = lane & 15, l4 = lane >> 4;

  auto pixof = [&](int e) {
    int p = e / WS, qc = e % WS;
    int h = ih * WS + p + S; if (h >= 120) h -= 120;
    int w = iw * WS + qc + S; if (w >= 120) w -= 120;
    return b * HW + h * 120 + w;
  };

  for (int idx = t; idx < L * 8; idx += NTHR) {
    int e = idx >> 3, c8 = (idx & 7) * 8;
    *reinterpret_cast<u32x4*>(&k_lds[e * 72 + c8]) =
        *reinterpret_cast<const u32x4*>(YQ + (size_t)pixof(e) * 192 + SI * 64 + c8);
  }
  for (int idx = t; idx < L * 8; idx += NTHR) {
    int e = idx >> 3, c8 = (idx & 7) * 8;
    u32x4 v = *reinterpret_cast<const u32x4*>(XP + (size_t)pixof(e) * 384 + SI * 128 + 64 + c8);
    const unsigned short* vh = reinterpret_cast<const unsigned short*>(&v);
#pragma unroll
    for (int j = 0; j < 8; ++j) vt_lds[(c8 + j) * PL + e] = vh[j];
  }
  if constexpr (KP > L) {
    for (int idx = t; idx < 64 * (KP - L); idx += NTHR)
      vt_lds[(idx / (KP - L)) * PL + L + (idx % (KP - L))] = 0;
  }

  bf16x8 af[SMAX][2];
#pragma unroll
  for (int si = 0; si < SMAX; ++si) {
    int ti = wave + si * NWAVE;
    if (ti < TT) {
      const unsigned short* qp =
          XP + (size_t)pixof(ti * 16 + l15) * 384 + SI * 128 + l4 * 8;
      af[si][0] = *reinterpret_cast<const bf16x8*>(qp);
      af[si][1] = *reinterpret_cast<const bf16x8*>(qp + 32);
    }
  }
  __syncthreads();

  f32x4 sacc[SMAX][TT];
#pragma unroll
  for (int si = 0; si < SMAX; ++si)
#pragma unroll
    for (int tj = 0; tj < TT; ++tj) sacc[si][tj] = f32x4{0.f, 0.f, 0.f, 0.f};
#pragma unroll
  for (int tj = 0; tj < TT; ++tj) {
    bf16x8 b0 = *reinterpret_cast<const bf16x8*>(&k_lds[(tj * 16 + l15) * 72 + l4 * 8]);
    bf16x8 b1 = *reinterpret_cast<const bf16x8*>(&k_lds[(tj * 16 + l15) * 72 + 32 + l4 * 8]);
#pragma unroll
    for (int si = 0; si < SMAX; ++si) {
      int ti = wave + si * NWAVE;
      if (ti < TT) {
        sacc[si][tj] = __builtin_amdgcn_mfma_f32_16x16x32_bf16(af[si][0], b0, sacc[si][tj], 0, 0, 0);
        sacc[si][tj] = __builtin_amdgcn_mfma_f32_16x16x32_bf16(af[si][1], b1, sacc[si][tj], 0, 0, 0);
      }
    }
  }

  float inv_[SMAX][4];
#pragma unroll
  for (int si = 0; si < SMAX; ++si) {
    int ti = wave + si * NWAVE;
    if (ti < TT) {
#pragma unroll
      for (int r = 0; r < 4; ++r) {
        float m = -1e30f;
#pragma unroll
        for (int tj = 0; tj < TT; ++tj) m = fmaxf(m, sacc[si][tj][r]);
#pragma unroll
        for (int mk = 1; mk < 16; mk <<= 1) m = fmaxf(m, __shfl_xor(m, mk, 64));
        float s = 0.f;
#pragma unroll
        for (int tj = 0; tj < TT; ++tj) {
          float e = __expf(sacc[si][tj][r] - m);
          sacc[si][tj][r] = e;
          s += e;
        }
#pragma unroll
        for (int mk = 1; mk < 16; mk <<= 1) s += __shfl_xor(s, mk, 64);
        inv_[si][r] = 1.f / s;
      }
    }
  }

  __syncthreads();

  if constexpr (KP > L) {
#pragma unroll
    for (int si = 0; si < SMAX; ++si) {
      int ti = wave + si * NWAVE;
      if (ti < TT)
        *reinterpret_cast<unsigned long long*>(
            &p_lds[(ti * 16 + l15) * PL + L + l4 * 4]) = 0ULL;
    }
  }

  float* aout = ATN + (size_t)win * L * L;
#pragma unroll
  for (int si = 0; si < SMAX; ++si) {
    int ti = wave + si * NWAVE;
    if (ti < TT) {
#pragma unroll
      for (int tj = 0; tj < TT; ++tj)
#pragma unroll
        for (int r = 0; r < 4; ++r) {
          float p = sacc[si][tj][r] * inv_[si][r];
          int row = ti * 16 + l4 * 4 + r, col = tj * 16 + l15;
          aout[row * L + col] = p;
          p_lds[row * PL + col] = f2bf(p);
        }
    }
  }
  __syncthreads();

#pragma unroll
  for (int si = 0; si < SMAX; ++si) {
    int ti = wave + si * NWAVE;
    if (ti < TT) {
      bf16x8 ap[KSTEPS];
#pragma unroll
      for (int kk = 0; kk < KSTEPS; ++kk)
        ap[kk] = *reinterpret_cast<const bf16x8*>(&p_lds[(ti * 16 + l15) * PL + kk * 32 + l4 * 8]);
      int opix[4];
#pragma unroll
      for (int r = 0; r < 4; ++r) opix[r] = pixof(ti * 16 + l4 * 4 + r);
#pragma unroll
      for (int cj = 0; cj < 4; ++cj) {
        f32x4 o = {0.f, 0.f, 0.f, 0.f};
#pragma unroll
        for (int kk = 0; kk < KSTEPS; ++kk) {
          bf16x8 bv = *reinterpret_cast<const bf16x8*>(&vt_lds[(cj * 16 + l15) * PL + kk * 32 + l4 * 8]);
          o = __builtin_amdgcn_mfma_f32_16x16x32_bf16(ap[kk], bv, o, 0, 0, 0);
        }
#pragma unroll
        for (int r = 0; r < 4; ++r)
          Z[(size_t)opix[r] * 192 + SI * 64 + cj * 16 + l15] = f2bf(o[r]);
      }
    }
  }
}

// ---------------- attn4: 4 windows/block, 1 wave each, zero barriers --------
__launch_bounds__(256, 2)
__global__ void attn4_kernel(const unsigned short* __restrict__ XP,
                             const unsigned short* __restrict__ YQ,
                             unsigned short* __restrict__ Z,
                             float* __restrict__ ATN) {
  __shared__ unsigned short kp[4][16 * 72];   // K rows then (alias) P [16][40]
  __shared__ unsigned short vt[4][64 * 40];   // V^T [ch][k], k zero-padded to 32
  const int t = threadIdx.x;
  const int wave = t >> 6, lane = t & 63, l15 = lane & 15, l4 = lane >> 4;
  const int win = blockIdx.x * 4 + wave;
  const int b = win / 900;
  const int r_ = win % 900;
  const int ih = r_ / 30, iw = r_ % 30;
  unsigned short* kl = kp[wave];
  unsigned short* vtl = vt[wave];

  auto pixof = [&](int e) {
    int h = ih * 4 + (e >> 2) + 2; if (h >= 120) h -= 120;
    int w = iw * 4 + (e & 3) + 2; if (w >= 120) w -= 120;
    return b * HW + h * 120 + w;
  };

#pragma unroll
  for (int it = 0; it < 2; ++it) {
    int idx = it * 64 + lane;
    int e = idx >> 3, c8 = (idx & 7) * 8;
    *reinterpret_cast<u32x4*>(&kl[e * 72 + c8]) =
        *reinterpret_cast<const u32x4*>(YQ + (size_t)pixof(e) * 192 + c8);
    u32x4 v = *reinterpret_cast<const u32x4*>(XP + (size_t)pixof(e) * 384 + 64 + c8);
    const unsigned short* vh = reinterpret_cast<const unsigned short*>(&v);
#pragma unroll
    for (int j = 0; j < 8; ++j) vtl[(c8 + j) * 40 + e] = vh[j];
  }
  {  // zero k-pad 16..31 of vt, ch = lane
    u32x4 z4 = {0, 0, 0, 0};
    *reinterpret_cast<u32x4*>(&vtl[lane * 40 + 16]) = z4;
    *reinterpret_cast<u32x4*>(&vtl[lane * 40 + 24]) = z4;
  }

  const unsigned short* qp = XP + (size_t)pixof(l15) * 384 + l4 * 8;
  bf16x8 af0 = *reinterpret_cast<const bf16x8*>(qp);
  bf16x8 af1 = *reinterpret_cast<const bf16x8*>(qp + 32);

  bf16x8 b0 = *reinterpret_cast<const bf16x8*>(&kl[l15 * 72 + l4 * 8]);
  bf16x8 b1 = *reinterpret_cast<const bf16x8*>(&kl[l15 * 72 + 32 + l4 * 8]);
  f32x4 sacc = {0.f, 0.f, 0.f, 0.f};
  sacc = __builtin_amdgcn_mfma_f32_16x16x32_bf16(af0, b0, sacc, 0, 0, 0);
  sacc = __builtin_amdgcn_mfma_f32_16x16x32_bf16(af1, b1, sacc, 0, 0, 0);

  float inv_[4];
#pragma unroll
  for (int r = 0; r < 4; ++r) {
    float m = sacc[r];
#pragma unroll
    for (int mk = 1; mk < 16; mk <<= 1) m = fmaxf(m, __shfl_xor(m, mk, 64));
    float e = __expf(sacc[r] - m);
    sacc[r] = e;
    float s = e;
#pragma unroll
    for (int mk = 1; mk < 16; mk <<= 1) s += __shfl_xor(s, mk, 64);
    inv_[r] = 1.f / s;
  }

  // P into kl alias [16][40], zero pad cols 16..31
  *reinterpret_cast<unsigned long long*>(&kl[l15 * 40 + 16 + l4 * 4]) = 0ULL;
  float* aout = ATN + (size_t)win * 256;
#pragma unroll
  for (int r = 0; r < 4; ++r) {
    float p = sacc[r] * inv_[r];
    int row = l4 * 4 + r;
    aout[row * 16 + l15] = p;
    kl[row * 40 + l15] = f2bf(p);
  }

  bf16x8 ap = *reinterpret_cast<const bf16x8*>(&kl[l15 * 40 + l4 * 8]);
  int opix[4];
#pragma unroll
  for (int r = 0; r < 4; ++r) opix[r] = pixof(l4 * 4 + r);
#pragma unroll
  for (int cj = 0; cj < 4; ++cj) {
    bf16x8 bv = *reinterpret_cast<const bf16x8*>(&vtl[(cj * 16 + l15) * 40 + l4 * 8]);
    f32x4 o = {0.f, 0.f, 0.f, 0.f};
    o = __builtin_amdgcn_mfma_f32_16x16x32_bf16(ap, bv, o, 0, 0, 0);
#pragma unroll
    for (int r = 0; r < 4; ++r)
      Z[(size_t)opix[r] * 192 + cj * 16 + l15] = f2bf(o[r]);
  }
}

// ---------------- conv_out: no-LDS MFMA loop + LDS-transpose epilogue -------
__launch_bounds__(256, 2)
__global__ void conv_out_kernel(const unsigned short* __restrict__ Z,
                                const unsigned short* __restrict__ Wo,
                                const float* __restrict__ bout,
                                float* __restrict__ Y1) {
  __shared__ float ep[4][48 * 68];
  const int t = threadIdx.x, wave = t >> 6, lane = t & 63;
  const int l15 = lane & 15, l4 = lane >> 4;
  const int b = blockIdx.x / 225, px0 = (blockIdx.x % 225) * 64;
  const unsigned short* Zb = Z + ((size_t)b * HW + px0) * 192;
  const int wo0 = wave * 48;

  f32x4 acc[3][4];
#pragma unroll
  for (int m = 0; m < 3; ++m) {
    f32x4 bv;
#pragma unroll
    for (int r = 0; r < 4; ++r) bv[r] = bout[wo0 + m * 16 + l4 * 4 + r];
#pragma unroll
    for (int n = 0; n < 4; ++n) acc[m][n] = bv;
  }

#pragma unroll
  for (int kc = 0; kc < 6; ++kc) {
    bf16x8 aw[3], bz[4];
#pragma unroll
    for (int m = 0; m < 3; ++m)
      aw[m] = *reinterpret_cast<const bf16x8*>(
          Wo + (size_t)(wo0 + m * 16 + l15) * 192 + kc * 32 + l4 * 8);
#pragma unroll
    for (int n = 0; n < 4; ++n)
      bz[n] = *reinterpret_cast<const bf16x8*>(
          Zb + (size_t)(n * 16 + l15) * 192 + kc * 32 + l4 * 8);
#pragma unroll
    for (int m = 0; m < 3; ++m)
#pragma unroll
      for (int n = 0; n < 4; ++n)
        acc[m][n] = __builtin_amdgcn_mfma_f32_16x16x32_bf16(aw[m], bz[n], acc[m][n], 0, 0, 0);
  }

  float* sl = ep[wave];
#pragma unroll
  for (int m = 0; m < 3; ++m)
#pragma unroll
    for (int n = 0; n < 4; ++n)
#pragma unroll
      for (int r = 0; r < 4; ++r)
        sl[(m * 16 + l4 * 4 + r) * 68 + n * 16 + l15] = acc[m][n][r];

  float* Yb = Y1 + (size_t)b * 192 * HW + px0;
#pragma unroll
  for (int i = 0; i < 3; ++i) {
    int row = i * 16 + (lane >> 2);
    int col0 = (lane & 3) * 16;
#pragma unroll
    for (int q = 0; q < 4; ++q) {
      f32x4 vv = *reinterpret_cast<const f32x4*>(&sl[row * 68 + col0 + q * 4]);
      *reinterpret_cast<f32x4*>(Yb + (size_t)(wo0 + row) * HW + col0 + q * 4) = vv;
    }
  }
}

// ---------------- launch ----------------------------------------------------
extern "C" void kernel_launch(void* const* d_in, const int* in_sizes, int n_in,
                              void* d_out, int out_size, void* d_ws, size_t ws_size,
                              hipStream_t stream) {
  const float* x = (const float*)d_in[0];
  const float* y = (const float*)d_in[1];
  const float* w_in = (const float*)d_in[2];
  const float* b_in = (const float*)d_in[3];
  const float* g = (const float*)d_in[4];
  const float* be = (const float*)d_in[5];
  const float* mu = (const float*)d_in[6];
  const float* va = (const float*)d_in[7];
  const float* w_out = (const float*)d_in[8];
  const float* b_out = (const float*)d_in[9];
  char* ws = (char*)d_ws;
  unsigned short* wx = (unsigned short*)(ws + 0);
  unsigned short* wy = (unsigned short*)(ws + 147456);
  unsigned short* wo = (unsigned short*)(ws + 221184);
  float* bx = (float*)(ws + 294912);
  float* by = (float*)(ws + 296448);
  unsigned short* xp = (unsigned short*)(ws + 297216);
  unsigned short* yq = (unsigned short*)(ws + 297216 + (size_t)115200 * 384 * 2);
  unsigned short* z  = (unsigned short*)(ws + 297216 + (size_t)115200 * 384 * 2 +
                                         (size_t)115200 * 192 * 2);
  float* out = (float*)d_out;

  prep_kernel<<<576, 256, 0, stream>>>(w_in, b_in, g, be, mu, va, w_out, wx, wy, wo, bx, by);
  conv_in_kernel<384><<<1800, 384, 0, stream>>>(x, wx, bx, xp);
  conv_in_kernel<192><<<1800, 384, 0, stream>>>(y, wy, by, yq);
  attn4_kernel<<<1800, 256, 0, stream>>>(xp, yq, z, out + 22118400);
  attn_kernel<8, 1, 256><<<1800, 256, 0, stream>>>(xp, yq, z, out + 23961600);
  attn_kernel<12, 2, 256><<<800, 256, 0, stream>>>(xp, yq, z, out + 31334400);
  conv_out_kernel<<<1800, 256, 0, stream>>>(z, wo, b_out, out);
}

// Round 4
// 248.318 us; speedup vs baseline: 1.1575x; 1.1575x over previous
//
#include <hip/hip_runtime.h>

typedef __bf16 bf16x8 __attribute__((ext_vector_type(8)));
typedef float f32x4 __attribute__((ext_vector_type(4)));
typedef unsigned int u32x4 __attribute__((ext_vector_type(4)));
typedef unsigned int u32x2 __attribute__((ext_vector_type(2)));

#define HW 14400
#define CIN 192

__device__ __forceinline__ unsigned short f2bf(float f) {
  unsigned int u = __builtin_bit_cast(unsigned int, f);
  u = (u + 0x7FFFu + ((u >> 16) & 1u)) >> 16;
  return (unsigned short)u;
}
__device__ __forceinline__ float bf2f(unsigned short h) {
  unsigned int u = ((unsigned int)h) << 16;
  return __builtin_bit_cast(float, u);
}
__device__ __forceinline__ unsigned cvtpk(float lo, float hi) {
  unsigned r;
  asm("v_cvt_pk_bf16_f32 %0, %1, %2" : "=v"(r) : "v"(lo), "v"(hi));
  return r;  // low16 = bf16(lo), high16 = bf16(hi), RTNE
}

// ---------------- prep: fold BN into conv weights, convert to bf16 ----------
__global__ void prep_kernel(const float* __restrict__ w_in, const float* __restrict__ b_in,
                            const float* __restrict__ g, const float* __restrict__ be,
                            const float* __restrict__ mu, const float* __restrict__ va,
                            const float* __restrict__ w_out,
                            unsigned short* __restrict__ wx, unsigned short* __restrict__ wy,
                            unsigned short* __restrict__ wo,
                            float* __restrict__ bx, float* __restrict__ by) {
  int idx = blockIdx.x * 256 + threadIdx.x;
  if (idx < 384 * 192) {
    int o = idx / 192;
    float s = g[o] * rsqrtf(va[o] + 1e-5f);
    wx[idx] = f2bf(w_in[idx] * s);
  } else if (idx < 384 * 192 + 192 * 192) {
    int j = idx - 384 * 192;
    int jo = j / 192, c = j % 192;
    int o = (jo >> 6) * 128 + (jo & 63);   // q-channel rows only
    float s = g[o] * rsqrtf(va[o] + 1e-5f);
    wy[j] = f2bf(w_in[o * 192 + c] * s);
  } else if (idx < 384 * 192 + 2 * 192 * 192) {
    int j = idx - (384 * 192 + 192 * 192);
    wo[j] = f2bf(w_out[j]);
  }
  if (idx < 384) {
    float s = g[idx] * rsqrtf(va[idx] + 1e-5f);
    bx[idx] = (b_in[idx] - mu[idx]) * s + be[idx];
  } else if (idx < 384 + 192) {
    int jo = idx - 384;
    int o = (jo >> 6) * 128 + (jo & 63);
    float s = g[o] * rsqrtf(va[o] + 1e-5f);
    by[jo] = (b_in[o] - mu[o]) * s + be[o];
  }
}

// ---------------- conv_in: [b,c,h,w] fp32 -> [px][NOUT] bf16 via MFMA -------
// R2 base + dbuf A (1 barrier/kc) + direct-global prefetched weights +
// cvt_pk staging with 8ch-block rotation (blk' = (blk + (row>>2)) & 3).
template <int NOUT>
__launch_bounds__(256, 2)
__global__ void conv_in_kernel(const float* __restrict__ X,
                               const unsigned short* __restrict__ Wb,
                               const float* __restrict__ bias,
                               unsigned short* __restrict__ Out) {
  constexpr int NT = NOUT / 64;  // N-tiles per wave (6 or 3)
  __shared__ unsigned short a_lds[2][64 * 40];
  const int t = threadIdx.x;
  const int wave = t >> 6, lane = t & 63;
  const int l15 = lane & 15, l4 = lane >> 4;
  const int b = blockIdx.x / 225;
  const int px0 = (blockIdx.x % 225) * 64;
  const float* Xb = X + (size_t)b * CIN * HW + px0;
  const int wo0 = wave * (NOUT / 4);

  f32x4 acc[4][NT];
#pragma unroll
  for (int n = 0; n < NT; ++n) {
    float bv = bias[wo0 + n * 16 + l15];
    f32x4 iv = {bv, bv, bv, bv};
#pragma unroll
    for (int m = 0; m < 4; ++m) acc[m][n] = iv;
  }

  // staging mapping: channels {c2, c2+1}, rows px4..px4+3
  const int c2 = (t >> 4) * 2, px4 = (t & 15) * 4;
  const int rotS = (t & 3);                      // (row>>2)&3 for staged rows
  const int C2 = (c2 & 7) + 8 * (((c2 >> 3) + rotS) & 3);
  f32x4 sv0, sv1;
  auto stage_load = [&](int kc) {
    sv0 = *reinterpret_cast<const f32x4*>(Xb + (size_t)(kc * 32 + c2) * HW + px4);
    sv1 = *reinterpret_cast<const f32x4*>(Xb + (size_t)(kc * 32 + c2 + 1) * HW + px4);
  };
  auto stage_write = [&](int buf) {
#pragma unroll
    for (int j = 0; j < 4; ++j)
      *reinterpret_cast<unsigned*>(&a_lds[buf][(px4 + j) * 40 + C2]) = cvtpk(sv0[j], sv1[j]);
  };
  auto loadW = [&](int kc, int n) {
    return *reinterpret_cast<const bf16x8*>(
        Wb + (size_t)(wo0 + n * 16 + l15) * CIN + kc * 32 + l4 * 8);
  };
  const int blkR = ((l4 + (l15 >> 2)) & 3) * 8;  // rotated frag block

  bf16x8 bw[NT], bwn[NT];
  stage_load(0);
  stage_write(0);
#pragma unroll
  for (int n = 0; n < NT; ++n) bw[n] = loadW(0, n);
  __syncthreads();

  for (int kc = 0; kc < 6; ++kc) {
    if (kc < 5) {
      stage_load(kc + 1);
#pragma unroll
      for (int n = 0; n < NT; ++n) bwn[n] = loadW(kc + 1, n);
    }
    bf16x8 af[4];
#pragma unroll
    for (int m = 0; m < 4; ++m)
      af[m] = *reinterpret_cast<const bf16x8*>(&a_lds[kc & 1][(m * 16 + l15) * 40 + blkR]);
#pragma unroll
    for (int n = 0; n < NT; ++n)
#pragma unroll
      for (int m = 0; m < 4; ++m)
        acc[m][n] = __builtin_amdgcn_mfma_f32_16x16x32_bf16(af[m], bw[n], acc[m][n], 0, 0, 0);
    if (kc < 5) {
      stage_write((kc + 1) & 1);
#pragma unroll
      for (int n = 0; n < NT; ++n) bw[n] = bwn[n];
    }
    __syncthreads();
  }

  unsigned short* Ob = Out + ((size_t)b * HW + px0) * NOUT;
#pragma unroll
  for (int m = 0; m < 4; ++m) {
#pragma unroll
    for (int r = 0; r < 4; ++r) {
      int px = m * 16 + l4 * 4 + r;
      unsigned short* dst = Ob + (size_t)px * NOUT + wo0 + l15;
#pragma unroll
      for (int n = 0; n < NT; ++n) dst[n * 16] = f2bf(acc[m][n][r]);
    }
  }
}

// ---------------- attention: reg-resident S, shfl softmax, MFMA PV ----------
template <int WS, int SI, int NTHR>
__launch_bounds__(NTHR, 2)
__global__ void attn_kernel(const unsigned short* __restrict__ XP,
                            const unsigned short* __restrict__ YQ,
                            unsigned short* __restrict__ Z,
                            float* __restrict__ ATN) {
  constexpr int S = WS / 2, L = WS * WS, NH = 120 / WS, TT = L / 16;
  constexpr int NWAVE = NTHR / 64;
  constexpr int SMAX = (TT + NWAVE - 1) / NWAVE;
  constexpr int KP = ((L + 31) / 32) * 32;
  constexpr int PL = KP + 8;
  constexpr int KSTEPS = KP / 32;
  constexpr int POOLE = (L * 72 > L * PL) ? L * 72 : L * PL;
  __shared__ unsigned short pool[POOLE];
  __shared__ unsigned short vt_lds[64 * PL];
  unsigned short* k_lds = pool;
  unsigned short* p_lds = pool;

  const int t = threadIdx.x;
  const int win = blockIdx.x;
  const int b = win / (NH * NH);
  const int r_ = win % (NH * NH);
  const int ih = r_ / NH, iw = r_ % NH;
  const int wave = t >> 6, lane = t & 63, l15 = lane & 15, l4 = lane >> 4;

  auto pixof = [&](int e) {
    int p = e / WS, qc = e % WS;
    int h = ih * WS + p + S; if (h >= 120) h -= 120;
    int w = iw * WS + qc + S; if (w >= 120) w -= 120;
    return b * HW + h * 120 + w;
  };

  for (int idx = t; idx < L * 8; idx += NTHR) {
    int e = idx >> 3, c8 = (idx & 7) * 8;
    *reinterpret_cast<u32x4*>(&k_lds[e * 72 + c8]) =
        *reinterpret_cast<const u32x4*>(YQ + (size_t)pixof(e) * 192 + SI * 64 + c8);
  }
  for (int idx = t; idx < L * 8; idx += NTHR) {
    int e = idx >> 3, c8 = (idx & 7) * 8;
    u32x4 v = *reinterpret_cast<const u32x4*>(XP + (size_t)pixof(e) * 384 + SI * 128 + 64 + c8);
    const unsigned short* vh = reinterpret_cast<const unsigned short*>(&v);
#pragma unroll
    for (int j = 0; j < 8; ++j) vt_lds[(c8 + j) * PL + e] = vh[j];
  }
  if constexpr (KP > L) {
    for (int idx = t; idx < 64 * (KP - L); idx += NTHR)
      vt_lds[(idx / (KP - L)) * PL + L + (idx % (KP - L))] = 0;
  }

  bf16x8 af[SMAX][2];
#pragma unroll
  for (int si = 0; si < SMAX; ++si) {
    int ti = wave + si * NWAVE;
    if (ti < TT) {
      const unsigned short* qp =
          XP + (size_t)pixof(ti * 16 + l15) * 384 + SI * 128 + l4 * 8;
      af[si][0] = *reinterpret_cast<const bf16x8*>(qp);
      af[si][1] = *reinterpret_cast<const bf16x8*>(qp + 32);
    }
  }
  __syncthreads();

  f32x4 sacc[SMAX][TT];
#pragma unroll
  for (int si = 0; si < SMAX; ++si)
#pragma unroll
    for (int tj = 0; tj < TT; ++tj) sacc[si][tj] = f32x4{0.f, 0.f, 0.f, 0.f};
#pragma unroll
  for (int tj = 0; tj < TT; ++tj) {
    bf16x8 b0 = *reinterpret_cast<const bf16x8*>(&k_lds[(tj * 16 + l15) * 72 + l4 * 8]);
    bf16x8 b1 = *reinterpret_cast<const bf16x8*>(&k_lds[(tj * 16 + l15) * 72 + 32 + l4 * 8]);
#pragma unroll
    for (int si = 0; si < SMAX; ++si) {
      int ti = wave + si * NWAVE;
      if (ti < TT) {
        sacc[si][tj] = __builtin_amdgcn_mfma_f32_16x16x32_bf16(af[si][0], b0, sacc[si][tj], 0, 0, 0);
        sacc[si][tj] = __builtin_amdgcn_mfma_f32_16x16x32_bf16(af[si][1], b1, sacc[si][tj], 0, 0, 0);
      }
    }
  }

  float inv_[SMAX][4];
#pragma unroll
  for (int si = 0; si < SMAX; ++si) {
    int ti = wave + si * NWAVE;
    if (ti < TT) {
#pragma unroll
      for (int r = 0; r < 4; ++r) {
        float m = -1e30f;
#pragma unroll
        for (int tj = 0; tj < TT; ++tj) m = fmaxf(m, sacc[si][tj][r]);
#pragma unroll
        for (int mk = 1; mk < 16; mk <<= 1) m = fmaxf(m, __shfl_xor(m, mk, 64));
        float s = 0.f;
#pragma unroll
        for (int tj = 0; tj < TT; ++tj) {
          float e = __expf(sacc[si][tj][r] - m);
          sacc[si][tj][r] = e;
          s += e;
        }
#pragma unroll
        for (int mk = 1; mk < 16; mk <<= 1) s += __shfl_xor(s, mk, 64);
        inv_[si][r] = 1.f / s;
      }
    }
  }

  __syncthreads();

  if constexpr (KP > L) {
#pragma unroll
    for (int si = 0; si < SMAX; ++si) {
      int ti = wave + si * NWAVE;
      if (ti < TT)
        *reinterpret_cast<unsigned long long*>(
            &p_lds[(ti * 16 + l15) * PL + L + l4 * 4]) = 0ULL;
    }
  }

  float* aout = ATN + (size_t)win * L * L;
#pragma unroll
  for (int si = 0; si < SMAX; ++si) {
    int ti = wave + si * NWAVE;
    if (ti < TT) {
#pragma unroll
      for (int tj = 0; tj < TT; ++tj)
#pragma unroll
        for (int r = 0; r < 4; ++r) {
          float p = sacc[si][tj][r] * inv_[si][r];
          int row = ti * 16 + l4 * 4 + r, col = tj * 16 + l15;
          aout[row * L + col] = p;
          p_lds[row * PL + col] = f2bf(p);
        }
    }
  }
  __syncthreads();

#pragma unroll
  for (int si = 0; si < SMAX; ++si) {
    int ti = wave + si * NWAVE;
    if (ti < TT) {
      bf16x8 ap[KSTEPS];
#pragma unroll
      for (int kk = 0; kk < KSTEPS; ++kk)
        ap[kk] = *reinterpret_cast<const bf16x8*>(&p_lds[(ti * 16 + l15) * PL + kk * 32 + l4 * 8]);
      int opix[4];
#pragma unroll
      for (int r = 0; r < 4; ++r) opix[r] = pixof(ti * 16 + l4 * 4 + r);
#pragma unroll
      for (int cj = 0; cj < 4; ++cj) {
        f32x4 o = {0.f, 0.f, 0.f, 0.f};
#pragma unroll
        for (int kk = 0; kk < KSTEPS; ++kk) {
          bf16x8 bv = *reinterpret_cast<const bf16x8*>(&vt_lds[(cj * 16 + l15) * PL + kk * 32 + l4 * 8]);
          o = __builtin_amdgcn_mfma_f32_16x16x32_bf16(ap[kk], bv, o, 0, 0, 0);
        }
#pragma unroll
        for (int r = 0; r < 4; ++r)
          Z[(size_t)opix[r] * 192 + SI * 64 + cj * 16 + l15] = f2bf(o[r]);
      }
    }
  }
}

// ---------------- conv_out: dbuf z LDS + direct-global weights + transpose --
__launch_bounds__(256, 2)
__global__ void conv_out_kernel(const unsigned short* __restrict__ Z,
                                const unsigned short* __restrict__ Wo,
                                const float* __restrict__ bout,
                                float* __restrict__ Y1) {
  __shared__ unsigned short z_lds[2][64 * 40];
  __shared__ float ep[4][48 * 68];
  const int t = threadIdx.x, wave = t >> 6, lane = t & 63;
  const int l15 = lane & 15, l4 = lane >> 4;
  const int b = blockIdx.x / 225, px0 = (blockIdx.x % 225) * 64;
  const unsigned short* Zb = Z + ((size_t)b * HW + px0) * 192;
  const int wo0 = wave * 48;

  f32x4 acc[3][4];
#pragma unroll
  for (int m = 0; m < 3; ++m) {
    f32x4 bv;
#pragma unroll
    for (int r = 0; r < 4; ++r) bv[r] = bout[wo0 + m * 16 + l4 * 4 + r];
#pragma unroll
    for (int n = 0; n < 4; ++n) acc[m][n] = bv;
  }

  const int zpx = t >> 2, zc8 = (t & 3) * 8;
  u32x4 zreg;
  auto zload = [&](int kc) {
    zreg = *reinterpret_cast<const u32x4*>(Zb + (size_t)zpx * 192 + kc * 32 + zc8);
  };
  auto zwrite = [&](int buf) {
    *reinterpret_cast<u32x4*>(&z_lds[buf][zpx * 40 + zc8]) = zreg;
  };
  auto loadWo = [&](int kc, int m) {
    return *reinterpret_cast<const bf16x8*>(
        Wo + (size_t)(wo0 + m * 16 + l15) * 192 + kc * 32 + l4 * 8);
  };

  bf16x8 aw[3], awn[3];
  zload(0);
  zwrite(0);
#pragma unroll
  for (int m = 0; m < 3; ++m) aw[m] = loadWo(0, m);
  __syncthreads();

  for (int kc = 0; kc < 6; ++kc) {
    if (kc < 5) {
      zload(kc + 1);
#pragma unroll
      for (int m = 0; m < 3; ++m) awn[m] = loadWo(kc + 1, m);
    }
    bf16x8 bz[4];
#pragma unroll
    for (int n = 0; n < 4; ++n)
      bz[n] = *reinterpret_cast<const bf16x8*>(&z_lds[kc & 1][(n * 16 + l15) * 40 + l4 * 8]);
#pragma unroll
    for (int m = 0; m < 3; ++m)
#pragma unroll
      for (int n = 0; n < 4; ++n)
        acc[m][n] = __builtin_amdgcn_mfma_f32_16x16x32_bf16(aw[m], bz[n], acc[m][n], 0, 0, 0);
    if (kc < 5) {
      zwrite((kc + 1) & 1);
#pragma unroll
      for (int m = 0; m < 3; ++m) aw[m] = awn[m];
    }
    __syncthreads();
  }

  float* sl = ep[wave];
#pragma unroll
  for (int m = 0; m < 3; ++m)
#pragma unroll
    for (int n = 0; n < 4; ++n)
#pragma unroll
      for (int r = 0; r < 4; ++r)
        sl[(m * 16 + l4 * 4 + r) * 68 + n * 16 + l15] = acc[m][n][r];

  float* Yb = Y1 + (size_t)b * 192 * HW + px0;
#pragma unroll
  for (int i = 0; i < 3; ++i) {
    int row = i * 16 + (lane >> 2);
    int col0 = (lane & 3) * 16;
#pragma unroll
    for (int q = 0; q < 4; ++q) {
      f32x4 vv = *reinterpret_cast<const f32x4*>(&sl[row * 68 + col0 + q * 4]);
      *reinterpret_cast<f32x4*>(Yb + (size_t)(wo0 + row) * HW + col0 + q * 4) = vv;
    }
  }
}

// ---------------- launch ----------------------------------------------------
extern "C" void kernel_launch(void* const* d_in, const int* in_sizes, int n_in,
                              void* d_out, int out_size, void* d_ws, size_t ws_size,
                              hipStream_t stream) {
  const float* x = (const float*)d_in[0];
  const float* y = (const float*)d_in[1];
  const float* w_in = (const float*)d_in[2];
  const float* b_in = (const float*)d_in[3];
  const float* g = (const float*)d_in[4];
  const float* be = (const float*)d_in[5];
  const float* mu = (const float*)d_in[6];
  const float* va = (const float*)d_in[7];
  const float* w_out = (const float*)d_in[8];
  const float* b_out = (const float*)d_in[9];
  char* ws = (char*)d_ws;
  unsigned short* wx = (unsigned short*)(ws + 0);
  unsigned short* wy = (unsigned short*)(ws + 147456);
  unsigned short* wo = (unsigned short*)(ws + 221184);
  float* bx = (float*)(ws + 294912);
  float* by = (float*)(ws + 296448);
  unsigned short* xp = (unsigned short*)(ws + 297216);
  unsigned short* yq = (unsigned short*)(ws + 297216 + (size_t)115200 * 384 * 2);
  unsigned short* z  = (unsigned short*)(ws + 297216 + (size_t)115200 * 384 * 2 +
                                         (size_t)115200 * 192 * 2);
  float* out = (float*)d_out;

  prep_kernel<<<576, 256, 0, stream>>>(w_in, b_in, g, be, mu, va, w_out, wx, wy, wo, bx, by);
  conv_in_kernel<384><<<1800, 256, 0, stream>>>(x, wx, bx, xp);
  conv_in_kernel<192><<<1800, 256, 0, stream>>>(y, wy, by, yq);
  attn_kernel<4, 0, 64><<<7200, 64, 0, stream>>>(xp, yq, z, out + 22118400);
  attn_kernel<8, 1, 256><<<1800, 256, 0, stream>>>(xp, yq, z, out + 23961600);
  attn_kernel<12, 2, 256><<<800, 256, 0, stream>>>(xp, yq, z, out + 31334400);
  conv_out_kernel<<<1800, 256, 0, stream>>>(z, wo, b_out, out);
}